// Round 4
// baseline (133.359 us; speedup 1.0000x reference)
//
#include <hip/hip_runtime.h>

// TF-IDF: out[b,v] = cnt[b,v] * idf[v] / sum_s idf[x[b,s]]
//   x: (512,1024) int32, idf: (50257,) fp32, out: (512,50257) fp32
//
// Round 4: two-pass sparse-compact structure.
//   pass 1 (1 block/row, 1024 thr, 100.5 KB LDS): packed u16-pair histogram
//     (built ONCE per row, not once per row-segment as round 3), dedup-scan
//     into compact (id, value=cnt*idf*inv_n) lists bucketed by 8192-wide
//     vocab segment, in d_ws. ~860 entries/row.
//   pass 2 (512 rows x 7 segments, 256 thr, 32 KB LDS -> 5 resident/CU):
//     zero LDS segment, PLAIN LDS stores of the compact entries (ids unique
//     after dedup -> no atomics), stream out with aligned float4 stores.
//     Near-pure store kernel, same shape as the 6.4 TB/s fill.
// Every output byte written exactly once; no global atomics.
// Falls back to the round-3 single-kernel if ws_size < ~29.4 MB.

constexpr int VOCAB = 50257;
constexpr int SEQ   = 1024;
constexpr int BATCH = 512;

constexpr int HWORDS   = (VOCAB + 1) / 2;           // 25129 packed u32 words
constexpr int HWORDS4  = ((HWORDS + 3) / 4) * 4;    // 25132 (uint4-padded)
constexpr int NTA      = 1024;                      // pass-1 threads (1 tok/thr)
constexpr int SEGSHIFT = 13;
constexpr int SEGLEN   = 1 << SEGSHIFT;             // 8192 floats = 32 KB LDS
constexpr int NSEG     = (VOCAB + SEGLEN - 1) / SEGLEN;  // 7 (last = 1105)
constexpr int MAXNZ    = 1024;                      // <= SEQ entries/segment
constexpr size_t COUNTS_BYTES = 16384;              // counts region (aligned)

// ---------------- pass 1: histogram + dedup + compact ----------------------
__global__ __launch_bounds__(NTA)
void tfidf_pass1(const int* __restrict__ x, const float* __restrict__ idf,
                 int* __restrict__ counts, int2* __restrict__ entries) {
    __shared__ __align__(16) unsigned int cnt[HWORDS4];
    __shared__ float red[NTA / 64];
    __shared__ int nzc[NSEG];

    const int b   = blockIdx.x;
    const int tid = threadIdx.x;

    // zero histogram (+padding) and segment counters
    {
        uint4* z = (uint4*)cnt;
        const uint4 z4 = make_uint4(0u, 0u, 0u, 0u);
        for (int i = tid; i < HWORDS4 / 4; i += NTA) z[i] = z4;
    }
    if (tid < NSEG) nzc[tid] = 0;
    __syncthreads();

    // one token per thread: histogram + normalizer partials
    const int tok = x[(size_t)b * SEQ + tid];
    const float my_idf = idf[tok];
    atomicAdd(&cnt[tok >> 1], (tok & 1) ? 65536u : 1u);

    float v = my_idf;
    #pragma unroll
    for (int off = 32; off > 0; off >>= 1) v += __shfl_down(v, off, 64);
    if ((tid & 63) == 0) red[tid >> 6] = v;
    __syncthreads();                      // histogram + partials complete

    float nsum = 0.0f;
    #pragma unroll
    for (int w = 0; w < NTA / 64; ++w) nsum += red[w];
    const float inv_n = 1.0f / nsum;

    // dedup-scan: emit (id, cnt*idf*inv_n) per nonzero slot, bucketed by seg
    for (int w4 = tid; w4 < HWORDS4 / 4; w4 += NTA) {
        const uint4 u4 = ((const uint4*)cnt)[w4];
        const unsigned uu[4] = {u4.x, u4.y, u4.z, u4.w};
        #pragma unroll
        for (int j = 0; j < 4; ++j) {
            const unsigned u = uu[j];
            if (u == 0u) continue;
            const int id0 = (w4 * 4 + j) * 2;
            const unsigned c0 = u & 0xffffu;
            const unsigned c1 = u >> 16;
            if (c0) {
                const int seg = id0 >> SEGSHIFT;
                const int pos = atomicAdd(&nzc[seg], 1);
                entries[((size_t)b * NSEG + seg) * MAXNZ + pos] =
                    make_int2(id0, __float_as_int((float)c0 * idf[id0] * inv_n));
            }
            if (c1) {
                const int id1 = id0 + 1;
                const int seg = id1 >> SEGSHIFT;
                const int pos = atomicAdd(&nzc[seg], 1);
                entries[((size_t)b * NSEG + seg) * MAXNZ + pos] =
                    make_int2(id1, __float_as_int((float)c1 * idf[id1] * inv_n));
            }
        }
    }
    __syncthreads();
    if (tid < NSEG) counts[b * NSEG + tid] = nzc[tid];
}

// ---------------- pass 2: zero LDS, scatter compact, stream out ------------
__global__ __launch_bounds__(256)
void tfidf_pass2(const int* __restrict__ counts, const int2* __restrict__ entries,
                 float* __restrict__ out) {
    __shared__ __align__(16) float seg[SEGLEN];

    const int bi  = blockIdx.x;
    const int b   = bi / NSEG;
    const int s   = bi - b * NSEG;
    const int tid = threadIdx.x;

    const int n = counts[b * NSEG + s];            // issue early (hides latency)
    const int2* __restrict__ e = entries + ((size_t)b * NSEG + s) * MAXNZ;

    {
        float4* z = (float4*)seg;
        const float4 z4 = make_float4(0.f, 0.f, 0.f, 0.f);
        for (int c = tid; c < SEGLEN / 4; c += 256) z[c] = z4;   // 8 iters
    }
    __syncthreads();

    for (int i = tid; i < n; i += 256) {           // ~120 entries: <1 iter avg
        const int2 p = e[i];
        seg[p.x & (SEGLEN - 1)] = __int_as_float(p.y);   // unique ids: plain store
    }
    __syncthreads();

    const int lo  = s << SEGSHIFT;
    const int len = (SEGLEN < VOCAB - lo) ? SEGLEN : (VOCAB - lo);
    const size_t g0 = (size_t)b * VOCAB + lo;
    float* __restrict__ o = out + g0;

    const int head = (int)((4 - (g0 & 3)) & 3);
    const int n4   = (len - head) >> 2;
    const int tail = len - head - (n4 << 2);

    if (tid < head) o[tid] = seg[tid];
    float4* __restrict__ p4 = (float4*)(o + head);
    for (int c = tid; c < n4; c += 256) {          // 8 float4/thread
        const int i = head + (c << 2);
        p4[c] = make_float4(seg[i], seg[i + 1], seg[i + 2], seg[i + 3]);
    }
    if (tid < tail) {
        const int i = head + (n4 << 2) + tid;
        o[i] = seg[i];
    }
}

// ---------------- fallback: round-3 single kernel (if ws too small) --------
constexpr int FSEG    = 4;
constexpr int FSEGLEN = (VOCAB + FSEG - 1) / FSEG;   // 12565

__global__ __launch_bounds__(256)
void tfidf_fallback(const int* __restrict__ x, const float* __restrict__ idf,
                    float* __restrict__ out) {
    __shared__ float seg[FSEGLEN];
    __shared__ float red[4];

    const int blk = blockIdx.x;
    const int b   = blk >> 2;
    const int s   = blk & 3;
    const int tid = threadIdx.x;

    const int lo  = s * FSEGLEN;
    const int len = (FSEGLEN < VOCAB - lo) ? FSEGLEN : (VOCAB - lo);

    const int4 t4 = ((const int4*)(x + (size_t)b * SEQ))[tid];
    {
        float4* z = (float4*)seg;
        const float4 z4 = make_float4(0.f, 0.f, 0.f, 0.f);
        for (int c = tid; c < FSEGLEN / 4; c += 256) z[c] = z4;
        if (tid < FSEGLEN - (FSEGLEN / 4) * 4) seg[(FSEGLEN / 4) * 4 + tid] = 0.f;
    }
    const float i0 = idf[t4.x], i1 = idf[t4.y], i2 = idf[t4.z], i3 = idf[t4.w];
    float v = (i0 + i1) + (i2 + i3);
    #pragma unroll
    for (int off = 32; off > 0; off >>= 1) v += __shfl_down(v, off, 64);
    if ((tid & 63) == 0) red[tid >> 6] = v;
    __syncthreads();
    const float inv_n = 1.0f / ((red[0] + red[1]) + (red[2] + red[3]));

    if (t4.x >= lo && t4.x < lo + len) atomicAdd(&seg[t4.x - lo], i0 * inv_n);
    if (t4.y >= lo && t4.y < lo + len) atomicAdd(&seg[t4.y - lo], i1 * inv_n);
    if (t4.z >= lo && t4.z < lo + len) atomicAdd(&seg[t4.z - lo], i2 * inv_n);
    if (t4.w >= lo && t4.w < lo + len) atomicAdd(&seg[t4.w - lo], i3 * inv_n);
    __syncthreads();

    const size_t g0 = (size_t)b * VOCAB + lo;
    float* __restrict__ o = out + g0;
    const int head = (int)((4 - (g0 & 3)) & 3);
    const int n4   = (len - head) >> 2;
    const int tail = len - head - (n4 << 2);

    if (tid < head) o[tid] = seg[tid];
    float4* __restrict__ p4 = (float4*)(o + head);
    for (int c = tid; c < n4; c += 256) {
        const int i = head + (c << 2);
        p4[c] = make_float4(seg[i], seg[i + 1], seg[i + 2], seg[i + 3]);
    }
    if (tid < tail) {
        const int i = head + (n4 << 2) + tid;
        o[i] = seg[i];
    }
}

extern "C" void kernel_launch(void* const* d_in, const int* in_sizes, int n_in,
                              void* d_out, int out_size, void* d_ws, size_t ws_size,
                              hipStream_t stream) {
    const int*   x   = (const int*)d_in[0];
    const float* idf = (const float*)d_in[1];
    float*       out = (float*)d_out;

    const size_t need = COUNTS_BYTES + (size_t)BATCH * NSEG * MAXNZ * sizeof(int2);
    if (ws_size >= need) {
        int*  counts  = (int*)d_ws;
        int2* entries = (int2*)((char*)d_ws + COUNTS_BYTES);
        tfidf_pass1<<<dim3(BATCH), dim3(NTA), 0, stream>>>(x, idf, counts, entries);
        tfidf_pass2<<<dim3(BATCH * NSEG), dim3(256), 0, stream>>>(counts, entries, out);
    } else {
        tfidf_fallback<<<dim3(BATCH * FSEG), dim3(256), 0, stream>>>(x, idf, out);
    }
}

// Round 5
// 126.507 us; speedup vs baseline: 1.0542x; 1.0542x over previous
//
#include <hip/hip_runtime.h>

// TF-IDF: out[b,v] = cnt[b,v] * idf[v] / sum_s idf[x[b,s]]
//   x: (512,1024) int32, idf: (50257,) fp32, out: (512,50257) fp32
//
// Round 5: R3's one-write-per-byte segmented skeleton, with ALL divergent
// gathers removed from the main kernel.
//   pre-kernel: inv_n[b] = 1/sum_s idf[x[b,s]]  (the only full-row divergent
//     gather), 512 tiny blocks -> 2 KB in d_ws. ~3-4 us.
//   main kernel: 512 rows x 7 segments of 8192 vocab, 256 thr, 64 KB LDS
//     (32 KB u32 counts + 32 KB idf slice) -> 2 resident/CU, 14 queued.
//     - zero cnt, COALESCED float4 load of the idf slice into LDS
//     - integer LDS histogram of in-segment tokens (no idf during scatter)
//     - write cnt[i]*idf_s[i]*inv_n with aligned float4 stores; sequential
//       conflict-free LDS reads; every output byte written exactly once.
//     No divergent VMEM at all -> the kernel is structurally the 6.4 TB/s
//     fill + trivial LDS traffic.

constexpr int VOCAB = 50257;
constexpr int SEQ   = 1024;
constexpr int BATCH = 512;

constexpr int SEGSHIFT = 13;
constexpr int SEGLEN   = 1 << SEGSHIFT;                  // 8192 floats
constexpr int NSEG     = (VOCAB + SEGLEN - 1) / SEGLEN;  // 7 (last = 1105)
constexpr int NT       = 256;

// ---------------- pre-kernel: per-row normalizer ---------------------------
__global__ __launch_bounds__(NT)
void inv_n_kernel(const int* __restrict__ x, const float* __restrict__ idf,
                  float* __restrict__ inv_n) {
    __shared__ float red[NT / 64];
    const int b   = blockIdx.x;
    const int tid = threadIdx.x;

    const int4 t4 = ((const int4*)(x + (size_t)b * SEQ))[tid];   // 4 tok/thr
    float v = (idf[t4.x] + idf[t4.y]) + (idf[t4.z] + idf[t4.w]);
    #pragma unroll
    for (int off = 32; off > 0; off >>= 1) v += __shfl_down(v, off, 64);
    if ((tid & 63) == 0) red[tid >> 6] = v;
    __syncthreads();
    if (tid == 0)
        inv_n[b] = 1.0f / ((red[0] + red[1]) + (red[2] + red[3]));
}

// ---------------- main kernel: segment histogram + stream-out --------------
__global__ __launch_bounds__(NT)
void tfidf_seg(const int* __restrict__ x, const float* __restrict__ idf,
               const float* __restrict__ inv_n_arr, float* __restrict__ out) {
    __shared__ __align__(16) unsigned int cnt[SEGLEN];   // 32 KB
    __shared__ __align__(16) float idf_s[SEGLEN];        // 32 KB

    const int bi  = blockIdx.x;
    const int s   = bi >> 9;           // segment (blocks grouped by segment
    const int b   = bi & (BATCH - 1);  //  -> concurrent blocks share idf slice)
    const int tid = threadIdx.x;

    const int lo  = s << SEGSHIFT;
    const int len = (SEGLEN < VOCAB - lo) ? SEGLEN : (VOCAB - lo);

    // issue coalesced token load + scalar inv_n early (latency hides below)
    const int4  t4   = ((const int4*)(x + (size_t)b * SEQ))[tid];
    const float rinv = inv_n_arr[b];

    // zero counts (8 uint4 iters/thread)
    {
        uint4* z = (uint4*)cnt;
        const uint4 z4 = make_uint4(0u, 0u, 0u, 0u);
        for (int c = tid; c < SEGLEN / 4; c += NT) z[c] = z4;
    }
    // coalesced idf slice -> LDS (guard the ragged last segment)
    {
        const float4* src = (const float4*)(idf + lo);   // lo is 32KB-aligned
        float4* dst = (float4*)idf_s;
        for (int c = tid; c < (len >> 2); c += NT) dst[c] = src[c];
        if (tid < (len & 3)) idf_s[(len & ~3) + tid] = idf[lo + (len & ~3) + tid];
    }
    __syncthreads();

    // integer histogram of in-segment tokens (unsigned trick: t<len covers t>=0)
    {
        const unsigned ul = (unsigned)len;
        unsigned t;
        t = (unsigned)(t4.x - lo); if (t < ul) atomicAdd(&cnt[t], 1u);
        t = (unsigned)(t4.y - lo); if (t < ul) atomicAdd(&cnt[t], 1u);
        t = (unsigned)(t4.z - lo); if (t < ul) atomicAdd(&cnt[t], 1u);
        t = (unsigned)(t4.w - lo); if (t < ul) atomicAdd(&cnt[t], 1u);
    }
    __syncthreads();

    // stream out: head / aligned float4 / tail — each byte written once
    const size_t g0 = (size_t)b * VOCAB + lo;
    float* __restrict__ o = out + g0;
    const int head = (int)((4 - (g0 & 3)) & 3);
    const int n4   = (len - head) >> 2;
    const int tail = len - head - (n4 << 2);

    if (tid < head) o[tid] = (float)cnt[tid] * idf_s[tid] * rinv;
    float4* __restrict__ p4 = (float4*)(o + head);
    for (int c = tid; c < n4; c += NT) {             // 8 iters/thread
        const int i = head + (c << 2);
        p4[c] = make_float4((float)cnt[i]     * idf_s[i]     * rinv,
                            (float)cnt[i + 1] * idf_s[i + 1] * rinv,
                            (float)cnt[i + 2] * idf_s[i + 2] * rinv,
                            (float)cnt[i + 3] * idf_s[i + 3] * rinv);
    }
    if (tid < tail) {
        const int i = head + (n4 << 2) + tid;
        o[i] = (float)cnt[i] * idf_s[i] * rinv;
    }
}

extern "C" void kernel_launch(void* const* d_in, const int* in_sizes, int n_in,
                              void* d_out, int out_size, void* d_ws, size_t ws_size,
                              hipStream_t stream) {
    const int*   x   = (const int*)d_in[0];
    const float* idf = (const float*)d_in[1];
    float*       out = (float*)d_out;
    float*       inv_n = (float*)d_ws;                 // 2 KB scratch

    inv_n_kernel<<<dim3(BATCH), dim3(NT), 0, stream>>>(x, idf, inv_n);
    tfidf_seg<<<dim3(BATCH * NSEG), dim3(NT), 0, stream>>>(x, idf, inv_n, out);
}

// Round 6
// 120.391 us; speedup vs baseline: 1.1077x; 1.0508x over previous
//
#include <hip/hip_runtime.h>

// TF-IDF: out[b,v] = cnt[b,v] * idf[v] / sum_s idf[x[b,s]]
//   x: (512,1024) int32, idf: (50257,) fp32, out: (512,50257) fp32
//
// Round 6 = Round 3 skeleton with ONE change: segment 12565 -> 8188 floats,
// so block LDS = 8188*4 + 16 (red) = exactly 32 KiB -> 5 resident blocks/CU
// (vs 3). Theory: R3's residual loss is phase CONVOYING -- few resident
// blocks with synchronized zero/gather/barrier phases leave the store pipe
// idle in bursts; more, smaller, staggered blocks keep stores continuously
// in flight. (R5 falsified the divergent-gather theory: gathers hide under
// the store drain; its occupancy drop + extra launch caused the regression.)
//
// Structure per block (row b, segment s of 7):
//   - int4 token load (coalesced), zero LDS segment, 4 idf gathers +
//     butterfly reduce -> inv_n (recomputed identically per row's blocks)
//   - LDS float atomicAdd of idf*inv_n for in-segment tokens (~167/block;
//     each slot accumulates copies of the same value -> deterministic)
//   - stream segment out: head / aligned float4 / tail, each output byte
//     written exactly once; no global atomics, no RMW traffic.

constexpr int VOCAB  = 50257;
constexpr int SEQ    = 1024;
constexpr int BATCH  = 512;
constexpr int SEGLEN = 8188;                             // *4 B + 16 = 32 KiB
constexpr int NSEG   = (VOCAB + SEGLEN - 1) / SEGLEN;    // 7 (last = 1129)
constexpr int NT     = 256;

__global__ __launch_bounds__(NT)
void tfidf_seg(const int* __restrict__ x, const float* __restrict__ idf,
               float* __restrict__ out) {
    __shared__ float seg[SEGLEN];    // 32,752 B
    __shared__ float red[4];         // +16 B = 32,768 B total -> 5 blocks/CU

    const int blk = blockIdx.x;
    const int b   = blk / NSEG;                  // row-major: consecutive
    const int s   = blk - b * NSEG;              // blocks share the x row
    const int tid = threadIdx.x;

    const int lo  = s * SEGLEN;
    const int len = (SEGLEN < VOCAB - lo) ? SEGLEN : (VOCAB - lo);

    // coalesced token load issued first (latency hides under LDS zeroing)
    const int4 t4 = ((const int4*)(x + (size_t)b * SEQ))[tid];

    // zero the LDS segment (SEGLEN % 4 == 0 -> pure float4, 8 iters)
    {
        float4* z = (float4*)seg;
        const float4 z4 = make_float4(0.f, 0.f, 0.f, 0.f);
        for (int c = tid; c < SEGLEN / 4; c += NT) z[c] = z4;
    }

    // normalizer: gather idf for this thread's 4 tokens (reused by scatter)
    const float i0 = idf[t4.x], i1 = idf[t4.y], i2 = idf[t4.z], i3 = idf[t4.w];
    float v = (i0 + i1) + (i2 + i3);
    #pragma unroll
    for (int off = 32; off > 0; off >>= 1) v += __shfl_down(v, off, 64);
    if ((tid & 63) == 0) red[tid >> 6] = v;
    __syncthreads();                  // zeroing + partials complete
    const float inv_n = 1.0f / ((red[0] + red[1]) + (red[2] + red[3]));

    // scatter in-segment tokens (unsigned trick covers tok < lo)
    {
        const unsigned ul = (unsigned)len;
        unsigned t;
        t = (unsigned)(t4.x - lo); if (t < ul) atomicAdd(&seg[t], i0 * inv_n);
        t = (unsigned)(t4.y - lo); if (t < ul) atomicAdd(&seg[t], i1 * inv_n);
        t = (unsigned)(t4.z - lo); if (t < ul) atomicAdd(&seg[t], i2 * inv_n);
        t = (unsigned)(t4.w - lo); if (t < ul) atomicAdd(&seg[t], i3 * inv_n);
    }
    __syncthreads();

    // stream out: head / aligned float4 / tail — each byte written once
    const size_t g0 = (size_t)b * VOCAB + lo;    // g0 % 4 == b % 4
    float* __restrict__ o = out + g0;
    const int head = (int)((4 - (g0 & 3)) & 3);
    const int n4   = (len - head) >> 2;
    const int tail = len - head - (n4 << 2);

    if (tid < head) o[tid] = seg[tid];
    float4* __restrict__ p4 = (float4*)(o + head);
    for (int c = tid; c < n4; c += NT) {         // 8 iters/thread
        const int i = head + (c << 2);
        p4[c] = make_float4(seg[i], seg[i + 1], seg[i + 2], seg[i + 3]);
    }
    if (tid < tail) {
        const int i = head + (n4 << 2) + tid;
        o[i] = seg[i];
    }
}

extern "C" void kernel_launch(void* const* d_in, const int* in_sizes, int n_in,
                              void* d_out, int out_size, void* d_ws, size_t ws_size,
                              hipStream_t stream) {
    const int*   x   = (const int*)d_in[0];
    const float* idf = (const float*)d_in[1];
    float*       out = (float*)d_out;
    tfidf_seg<<<dim3(BATCH * NSEG), dim3(NT), 0, stream>>>(x, idf, out);
}

// Round 7
// 111.734 us; speedup vs baseline: 1.1935x; 1.0775x over previous
//
#include <hip/hip_runtime.h>

// TF-IDF: out[b,v] = cnt[b,v] * idf[v] / sum_s idf[x[b,s]]
//   x: (512,1024) int32, idf: (50257,) fp32, out: (512,50257) fp32
//
// Round 7 = Round 1 structure (one 1024-thr block per row, u16-pair-packed
// LDS histogram, ONE divergent idf gather per token -- the round-6 lesson:
// kernel cost ~ store drain + gather-split count, and segmenting multiplies
// gathers by NSEG) with the single fix R1 needed: the write phase uses
// float4 stores (13 independent unrolled iterations/thread) instead of 49
// dependent scalar stores. LDS count reads stay scalar (b32) to dodge the
// odd-offset unpack problem; idf reads are stride-4 scalar, L2-resident.
// Every output byte written exactly once; no global atomics.

constexpr int VOCAB   = 50257;
constexpr int SEQ     = 1024;
constexpr int BATCH   = 512;
constexpr int HWORDS  = (VOCAB + 1) / 2;          // 25129 packed u32 words
constexpr int HWORDS4 = ((HWORDS + 3) / 4) * 4;   // 25132 -> 100,528 B LDS
constexpr int NT      = 1024;                     // one token per thread

__global__ __launch_bounds__(NT)
void tfidf_kernel(const int* __restrict__ x,
                  const float* __restrict__ idf,
                  float* __restrict__ out) {
    __shared__ __align__(16) unsigned int cnt[HWORDS4];
    __shared__ float red[NT / 64];

    const int b   = blockIdx.x;
    const int tid = threadIdx.x;

    // token load first (global latency hides under LDS zeroing)
    const int tok = x[(size_t)b * SEQ + tid];

    // zero the packed histogram (uint4, 7 iters)
    {
        uint4* z = (uint4*)cnt;
        const uint4 z4 = make_uint4(0u, 0u, 0u, 0u);
        for (int i = tid; i < HWORDS4 / 4; i += NT) z[i] = z4;
    }

    // the ONLY divergent gather: idf[tok], once per token
    const float my_idf = idf[tok];
    __syncthreads();                       // zeroing complete

    // histogram: two u16 counts per u32 word; max count 1024 < 2^16 -> no carry
    atomicAdd(&cnt[tok >> 1], (tok & 1) ? 65536u : 1u);

    // normalizer
    float v = my_idf;
    #pragma unroll
    for (int off = 32; off > 0; off >>= 1) v += __shfl_down(v, off, 64);
    if ((tid & 63) == 0) red[tid >> 6] = v;
    __syncthreads();                       // histogram + partials complete
    float nsum = 0.0f;
    #pragma unroll
    for (int w = 0; w < NT / 64; ++w) nsum += red[w];
    const float inv_n = 1.0f / nsum;

    // ---- write phase: head / aligned float4 / tail ----------------------
    float* __restrict__ orow = out + (size_t)b * VOCAB;   // offset%4 == b%4
    const int head = (4 - (b & 3)) & 3;
    const int n4   = (VOCAB - head) >> 2;
    const int tail = VOCAB - head - (n4 << 2);

    auto elem = [&](int vi) -> float {
        const unsigned w = cnt[vi >> 1];
        const unsigned c = (vi & 1) ? (w >> 16) : (w & 0xffffu);
        return (float)c * idf[vi] * inv_n;
    };

    if (tid < head) orow[tid] = elem(tid);
    float4* __restrict__ p4 = (float4*)(orow + head);
    #pragma unroll 4
    for (int c = tid; c < n4; c += NT) {   // ~13 independent f4 iters/thread
        const int i = head + (c << 2);
        p4[c] = make_float4(elem(i), elem(i + 1), elem(i + 2), elem(i + 3));
    }
    if (tid < tail) {
        const int i = head + (n4 << 2) + tid;
        orow[i] = elem(i);
    }
}

extern "C" void kernel_launch(void* const* d_in, const int* in_sizes, int n_in,
                              void* d_out, int out_size, void* d_ws, size_t ws_size,
                              hipStream_t stream) {
    const int*   x   = (const int*)d_in[0];
    const float* idf = (const float*)d_in[1];
    float*       out = (float*)d_out;
    tfidf_kernel<<<dim3(BATCH), dim3(NT), 0, stream>>>(x, idf, out);
}

// Round 8
// 109.997 us; speedup vs baseline: 1.2124x; 1.0158x over previous
//
#include <hip/hip_runtime.h>

// TF-IDF: out[b,v] = cnt[b,v] * idf[v] / sum_s idf[x[b,s]]
//   x: (512,1024) int32, idf: (50257,) fp32, out: (512,50257) fp32
//
// Round 8 = Round 7 (one 1024-thr block per row, u16-pair-packed full-vocab
// LDS histogram, ONE divergent idf gather per token) with the write loop's
// READS vectorized to match its float4 stores:
//   per 4 outputs: 1 ds_read_b64 (uint2 = 4 packed counts, 8B-aligned)
//                + 1 global_load_dwordx4 (idf, 16B-aligned)
//                + 1 16B store (4B-aligned when b%4!=0 -> packed-struct
//                  store; gfx9+ handles unaligned global wide stores, and
//                  the wave's span stays contiguous so coalescing holds).
// Memory instrs in the hot loop: 9 -> 3 per 16 bytes stored (R7 had 4
// ds_read_b32 + 4 stride-4 scalar idf loads per float4).
// Every output byte written exactly once; no global atomics.

constexpr int VOCAB   = 50257;
constexpr int SEQ     = 1024;
constexpr int BATCH   = 512;
constexpr int HWORDS  = (VOCAB + 1) / 2;          // 25129 packed u32 words
constexpr int HWORDS4 = ((HWORDS + 3) / 4) * 4;   // 25132 -> 100,528 B LDS
constexpr int NT      = 1024;                     // one token per thread
constexpr int NGROUP  = VOCAB >> 2;               // 12564 aligned vocab quads

struct __attribute__((packed)) f4p { float4 v; };  // relaxed-alignment store

__global__ __launch_bounds__(NT)
void tfidf_kernel(const int* __restrict__ x,
                  const float* __restrict__ idf,
                  float* __restrict__ out) {
    __shared__ __align__(16) unsigned int cnt[HWORDS4];
    __shared__ float red[NT / 64];

    const int b   = blockIdx.x;
    const int tid = threadIdx.x;

    // token load first (global latency hides under LDS zeroing)
    const int tok = x[(size_t)b * SEQ + tid];

    // zero the packed histogram (uint4, ~6 iters/thread)
    {
        uint4* z = (uint4*)cnt;
        const uint4 z4 = make_uint4(0u, 0u, 0u, 0u);
        for (int i = tid; i < HWORDS4 / 4; i += NT) z[i] = z4;
    }

    // the ONLY divergent gather: idf[tok], once per token
    const float my_idf = idf[tok];
    __syncthreads();                       // zeroing complete

    // histogram: two u16 counts per u32 word; max count 1024 < 2^16 -> no carry
    atomicAdd(&cnt[tok >> 1], (tok & 1) ? 65536u : 1u);

    // normalizer
    float v = my_idf;
    #pragma unroll
    for (int off = 32; off > 0; off >>= 1) v += __shfl_down(v, off, 64);
    if ((tid & 63) == 0) red[tid >> 6] = v;
    __syncthreads();                       // histogram + partials complete
    float nsum = 0.0f;
    #pragma unroll
    for (int w = 0; w < NT / 64; ++w) nsum += red[w];
    const float inv_n = 1.0f / nsum;

    // ---- write phase: vocab-aligned quads ------------------------------
    float* __restrict__ orow = out + (size_t)b * VOCAB;
    const float4* __restrict__ idf4 = (const float4*)idf;   // 16B-aligned
    f4p* __restrict__ o4 = (f4p*)orow;                      // 4B-aligned ok

    for (int c = tid; c < NGROUP; c += NT) {   // ~12.3 independent iters
        const uint2  w = *(const uint2*)&cnt[2 * c];        // ds_read_b64
        const float4 f = idf4[c];                           // dwordx4 load
        float4 r;
        r.x = (float)(w.x & 0xffffu) * f.x * inv_n;
        r.y = (float)(w.x >> 16)     * f.y * inv_n;
        r.z = (float)(w.y & 0xffffu) * f.z * inv_n;
        r.w = (float)(w.y >> 16)     * f.w * inv_n;
        o4[c].v = r;                                        // dwordx4 store
    }
    if (tid == 0) {                            // tail: vi = 50256 (even -> low)
        orow[VOCAB - 1] =
            (float)(cnt[(VOCAB - 1) >> 1] & 0xffffu) * idf[VOCAB - 1] * inv_n;
    }
}

extern "C" void kernel_launch(void* const* d_in, const int* in_sizes, int n_in,
                              void* d_out, int out_size, void* d_ws, size_t ws_size,
                              hipStream_t stream) {
    const int*   x   = (const int*)d_in[0];
    const float* idf = (const float*)d_in[1];
    float*       out = (float*)d_out;
    tfidf_kernel<<<dim3(BATCH), dim3(NT), 0, stream>>>(x, idf, out);
}